// Round 9
// baseline (246.949 us; speedup 1.0000x reference)
//
#include <hip/hip_runtime.h>

// RelationGAT fused flash-attention, MFMA fp16 (gfx950).
// out = softmax((x@Wq^T+bq) @ (nb@Wk^T+bk)^T) @ nb @ Wv^T + bv
// bk cancels in softmax. Q~ = x@G + u, G = Wq^T Wk, u = bq^T Wk; K=V=raw nb.
// R8 was clean (no spills, 133 us) but latency-bound: no pipe >27% busy,
// ~2 blocks/CU, 16 barrier-lockstep phases. R9: K fragments read DIRECTLY
// from global nb (L2-resident 256 KB, L1 reuse across waves) -- no sK, no
// K staging, no K barriers; V^T-only LDS staging in 256-j stages (8 barriers
// total, packed b32 writes); per-lane partial l (reduce once at end);
// __launch_bounds__(256,4) to target 4 blocks/CU.

#define N_ROWS 100000

typedef __attribute__((ext_vector_type(8))) _Float16 half8;
typedef __attribute__((ext_vector_type(4))) float    f32x4;

#define MFMA16(a,b,c) __builtin_amdgcn_mfma_f32_16x16x32_f16((a),(b),(c),0,0,0)

static __device__ __forceinline__ f32x4 zero4() {
    f32x4 v = {0.f, 0.f, 0.f, 0.f};
    return v;
}
static __device__ __forceinline__ unsigned pack2(float a, float b) {
    union { _Float16 h[2]; unsigned u; } p;
    p.h[0] = (_Float16)a; p.h[1] = (_Float16)b;
    return p.u;
}

// LDS map (36608 B total):
//  main:   sVT [0,33792)  fp16 [64][264]  (d-major transpose of 256-j tile)
//  setup1: sWk [0,16384) sWq [16384,32768) f32 staged weights
//  setup2: per-wave slice [16][68] f32 at wv*4352 (0..17408)
//          sGh [17408,26624) sGl [26624,35840) fp16 G^T hi/lo [64][72]
//  fixed:  sU [36096,36352) f32 ; sBv [36352,36608) f32
__global__ __launch_bounds__(256, 4)
void attn_kernel(const float* __restrict__ x,  const float* __restrict__ nb,
                 const float* __restrict__ Wq, const float* __restrict__ bq,
                 const float* __restrict__ Wk, const float* __restrict__ Wv,
                 const float* __restrict__ bv, float* __restrict__ out)
{
    __shared__ __align__(16) char smem[36608];
    unsigned short* sVT = (unsigned short*)smem;              // [64][264] fp16
    unsigned short* sGh = (unsigned short*)(smem + 17408);    // setup: GT hi
    unsigned short* sGl = (unsigned short*)(smem + 26624);    // setup: GT lo
    float* sWk = (float*)smem;                                // setup-1
    float* sWq = (float*)(smem + 16384);                      // setup-1
    float* sU  = (float*)(smem + 36096);
    float* sBv = (float*)(smem + 36352);

    const int tid  = threadIdx.x;
    const int lane = tid & 63;
    const int wv   = tid >> 6;     // wave 0..3
    const int Q    = lane >> 4;    // quad 0..3
    const int c    = lane & 15;    // col 0..15
    const int rbase = blockIdx.x * 128 + wv * 32;   // this wave's 32 q-rows

    // ---------------- setup 1: stage Wk/Wq, compute G^T hi/lo, u ----------------
    {
        const float4* wk4 = (const float4*)Wk;
        const float4* wq4 = (const float4*)Wq;
        float4* dk = (float4*)sWk;
        float4* dq = (float4*)sWq;
        #pragma unroll
        for (int u = 0; u < 4; u++) {
            dk[u * 256 + tid] = wk4[u * 256 + tid];
            dq[u * 256 + tid] = wq4[u * 256 + tid];
        }
    }
    __syncthreads();
    float g[16];
    float uu = 0.f;
    {
        const int e2  = tid & 63;        // GT row (k-embedding dim)
        const int e1g = wv * 16;         // 16 columns (x-embedding dim)
        #pragma unroll
        for (int q = 0; q < 16; q++) g[q] = 0.f;
        for (int w = 0; w < 64; w++) {
            float kv = sWk[w * 64 + e2];
            const float* wqp = sWq + w * 64 + e1g;
            #pragma unroll
            for (int q = 0; q < 16; q++) g[q] = fmaf(wqp[q], kv, g[q]);
        }
        if (tid < 64)
            for (int w = 0; w < 64; w++) uu = fmaf(bq[w], sWk[w * 64 + tid], uu);
    }
    __syncthreads();   // sWk/sWq dead
    {
        const int e2 = tid & 63, e1g = wv * 16;
        union { half8 h; uint4 u; } ph0, pl0, ph1, pl1;
        #pragma unroll
        for (int i = 0; i < 8; i++) {
            _Float16 h0 = (_Float16)g[i];
            ph0.h[i] = h0; pl0.h[i] = (_Float16)(g[i] - (float)h0);
            _Float16 h1 = (_Float16)g[8 + i];
            ph1.h[i] = h1; pl1.h[i] = (_Float16)(g[8 + i] - (float)h1);
        }
        *(uint4*)(sGh + e2 * 72 + e1g)     = ph0.u;
        *(uint4*)(sGh + e2 * 72 + e1g + 8) = ph1.u;
        *(uint4*)(sGl + e2 * 72 + e1g)     = pl0.u;
        *(uint4*)(sGl + e2 * 72 + e1g + 8) = pl1.u;
        if (tid < 64) { sU[tid] = uu; sBv[tid] = bv[tid]; }
    }
    __syncthreads();

    // ------- setup 2: Q~^T = G^T x^T via MFMA -> q-frags hi/lo (fully unrolled) -------
    half8 qh[2][2], ql[2][2];   // [rt][ks] -- static indices ONLY
    float* slice = (float*)(smem + wv * 4352);   // [16][68] f32 per wave
    #pragma unroll
    for (int rt = 0; rt < 2; rt++) {
        int row = rbase + rt * 16 + c;
        if (row > N_ROWS - 1) row = N_ROWS - 1;
        half8 xh[2], xl[2];
        #pragma unroll
        for (int ks = 0; ks < 2; ks++) {
            const float* xp = x + (size_t)row * 64 + ks * 32 + Q * 8;
            float a[8];
            *(float4*)a       = *(const float4*)xp;
            *(float4*)(a + 4) = *(const float4*)(xp + 4);
            #pragma unroll
            for (int i = 0; i < 8; i++) {
                _Float16 h = (_Float16)a[i];
                xh[ks][i] = h;
                xl[ks][i] = (_Float16)(a[i] - (float)h);
            }
        }
        #pragma unroll
        for (int mt = 0; mt < 4; mt++) {
            f32x4 Cm = zero4();
            #pragma unroll
            for (int ks = 0; ks < 2; ks++) {
                half8 gh = *(const half8*)(sGh + (mt * 16 + c) * 72 + ks * 32 + Q * 8);
                half8 gl = *(const half8*)(sGl + (mt * 16 + c) * 72 + ks * 32 + Q * 8);
                Cm = MFMA16(gh, xh[ks], Cm);   // D[dout][x-row]
                Cm = MFMA16(gh, xl[ks], Cm);
                Cm = MFMA16(gl, xh[ks], Cm);
            }
            *(f32x4*)(slice + c * 68 + mt * 16 + 4 * Q) = Cm;
        }
        __builtin_amdgcn_s_waitcnt(0);   // wave-local LDS RAW
        #pragma unroll
        for (int ks = 0; ks < 2; ks++) {
            const float* qp = slice + c * 68 + ks * 32 + Q * 8;
            const float* up = sU + ks * 32 + Q * 8;
            #pragma unroll
            for (int i = 0; i < 8; i++) {
                float val = qp[i] + up[i];
                _Float16 h = (_Float16)val;
                qh[rt][ks][i] = h;
                ql[rt][ks][i] = (_Float16)(val - (float)h);
            }
        }
        __builtin_amdgcn_s_waitcnt(0);   // reads done before rt=1 overwrites slice
    }
    __syncthreads();

    // ---------------- main flash loop: M=1024 in 4 stages of 256 ----------------
    f32x4 acc[2][4];   // [qt][dt] agg^T C-frags
    #pragma unroll
    for (int qt = 0; qt < 2; qt++)
        #pragma unroll
        for (int dt = 0; dt < 4; dt++) acc[qt][dt] = zero4();
    float mrow[2]  = { -3.0e38f, -3.0e38f };
    float lpart[2] = { 0.f, 0.f };          // per-lane partial (reduced at end)
    const int roff = 8 * (c >> 2) + (c & 3);  // K logical-row offset for A-frag

    #pragma unroll 1
    for (int st = 0; st < 4; st++) {
        // ---- stage V^T only: 256 j rows, packed b32 row-pair writes ----
        {
            const int jp = (tid >> 1) * 2;       // even row 0..254
            const int dh = (tid & 1) * 32;       // d half
            const float* r0 = nb + (size_t)(st * 256 + jp) * 64 + dh;
            #pragma unroll
            for (int dd = 0; dd < 32; dd += 4) {
                float4 a0 = *(const float4*)(r0 + dd);
                float4 a1 = *(const float4*)(r0 + 64 + dd);
                *(unsigned*)(sVT + (dh + dd + 0) * 264 + jp) = pack2(a0.x, a1.x);
                *(unsigned*)(sVT + (dh + dd + 1) * 264 + jp) = pack2(a0.y, a1.y);
                *(unsigned*)(sVT + (dh + dd + 2) * 264 + jp) = pack2(a0.z, a1.z);
                *(unsigned*)(sVT + (dh + dd + 3) * 264 + jp) = pack2(a0.w, a1.w);
            }
        }
        __syncthreads();

        #pragma unroll 1
        for (int jc = 0; jc < 8; jc++) {
            const int jb  = st * 256 + jc * 32;   // global j base
            const int jbl = jc * 32;              // local j base in sVT
            // ---- K fragments straight from global (L1/L2-resident) ----
            const float* kr0 = nb + (size_t)(jb + roff) * 64 + Q * 8;  // t=0
            const float* kr1 = kr0 + 4 * 64;                           // t=1 (+4 j)
            float4 f00 = *(const float4*)(kr0);
            float4 f01 = *(const float4*)(kr0 + 4);
            float4 f02 = *(const float4*)(kr0 + 32);
            float4 f03 = *(const float4*)(kr0 + 36);
            float4 f10 = *(const float4*)(kr1);
            float4 f11 = *(const float4*)(kr1 + 4);
            float4 f12 = *(const float4*)(kr1 + 32);
            float4 f13 = *(const float4*)(kr1 + 36);
            half8 k00, k01, k10, k11;   // [t][k-half]
            #pragma unroll
            for (int e = 0; e < 4; e++) {
                k00[e]     = (_Float16)((const float*)&f00)[e];
                k00[4 + e] = (_Float16)((const float*)&f01)[e];
                k01[e]     = (_Float16)((const float*)&f02)[e];
                k01[4 + e] = (_Float16)((const float*)&f03)[e];
                k10[e]     = (_Float16)((const float*)&f10)[e];
                k10[4 + e] = (_Float16)((const float*)&f11)[e];
                k11[e]     = (_Float16)((const float*)&f12)[e];
                k11[4 + e] = (_Float16)((const float*)&f13)[e];
            }
            // ---- QK: 4 independent MFMA chains ----
            f32x4 S[2][2];   // [t][qt]
            #pragma unroll
            for (int qt = 0; qt < 2; qt++) {
                f32x4 s0 = MFMA16(k00, qh[qt][0], zero4());
                s0 = MFMA16(k01, qh[qt][1], s0);
                s0 = MFMA16(k00, ql[qt][0], s0);
                s0 = MFMA16(k01, ql[qt][1], s0);
                S[0][qt] = s0;
                f32x4 s1 = MFMA16(k10, qh[qt][0], zero4());
                s1 = MFMA16(k11, qh[qt][1], s1);
                s1 = MFMA16(k10, ql[qt][0], s1);
                s1 = MFMA16(k11, ql[qt][1], s1);
                S[1][qt] = s1;
            }
            // ---- online softmax (per-lane l partial) + P->fp16 ----
            half8 pB[2];
            #pragma unroll
            for (int qt = 0; qt < 2; qt++) {
                float cm = fmaxf(fmaxf(fmaxf(S[0][qt][0], S[0][qt][1]),
                                       fmaxf(S[0][qt][2], S[0][qt][3])),
                                 fmaxf(fmaxf(S[1][qt][0], S[1][qt][1]),
                                       fmaxf(S[1][qt][2], S[1][qt][3])));
                cm = fmaxf(cm, __shfl_xor(cm, 16));
                cm = fmaxf(cm, __shfl_xor(cm, 32));
                const float mn = fmaxf(mrow[qt], cm);
                const float sc = __expf(mrow[qt] - mn);
                mrow[qt] = mn;
                float p[8]; float ps = 0.f;
                #pragma unroll
                for (int r = 0; r < 4; r++) { p[r] = __expf(S[0][qt][r] - mn); ps += p[r]; }
                #pragma unroll
                for (int r = 0; r < 4; r++) { p[4 + r] = __expf(S[1][qt][r] - mn); ps += p[4 + r]; }
                lpart[qt] = lpart[qt] * sc + ps;   // scale uniform across quads
                #pragma unroll
                for (int dt = 0; dt < 4; dt++)
                    #pragma unroll
                    for (int r = 0; r < 4; r++) acc[qt][dt][r] *= sc;
                #pragma unroll
                for (int i = 0; i < 8; i++) pB[qt][i] = (_Float16)p[i];
            }
            // ---- PV from sVT ----
            #pragma unroll
            for (int dt = 0; dt < 4; dt++) {
                half8 vA = *(const half8*)(sVT + (dt * 16 + c) * 264 + jbl + Q * 8);
                acc[0][dt] = MFMA16(vA, pB[0], acc[0][dt]);
                acc[1][dt] = MFMA16(vA, pB[1], acc[1][dt]);
            }
        }
        __syncthreads();
    }

    // ---------------- epilogue: reduce l, out = (agg/l) @ Wv^T + bv ----------------
    float rl[2];
    #pragma unroll
    for (int qt = 0; qt < 2; qt++) {
        float lv = lpart[qt];
        lv += __shfl_xor(lv, 16);
        lv += __shfl_xor(lv, 32);
        rl[qt] = 1.f / lv;
    }
    #pragma unroll
    for (int qt = 0; qt < 2; qt++)
        #pragma unroll
        for (int dt = 0; dt < 4; dt++)
            #pragma unroll
            for (int r = 0; r < 4; r++) acc[qt][dt][r] *= rl[qt];
    half8 wf[4][2];
    #pragma unroll
    for (int mt = 0; mt < 4; mt++)
        #pragma unroll
        for (int ks = 0; ks < 2; ks++) {
            const float* wp = Wv + (size_t)(mt * 16 + c) * 64 + ks * 32 + Q * 8;
            #pragma unroll
            for (int i = 0; i < 8; i++) wf[mt][ks][i] = (_Float16)wp[i];
        }
    const int srcA = 32 * (Q & 1) + c;
    const int srcB = srcA + 16;
    const bool hi = (Q >> 1) & 1;
    f32x4 o[2][4];
    #pragma unroll
    for (int qt = 0; qt < 2; qt++) {
        half8 pe[2];
        #pragma unroll
        for (int ks = 0; ks < 2; ks++) {
            #pragma unroll
            for (int r = 0; r < 4; r++) {
                float a0 = __shfl(acc[qt][2 * ks + 0][r], srcA);
                float a1 = __shfl(acc[qt][2 * ks + 1][r], srcA);
                float b0 = __shfl(acc[qt][2 * ks + 0][r], srcB);
                float b1 = __shfl(acc[qt][2 * ks + 1][r], srcB);
                pe[ks][r]     = (_Float16)(hi ? a1 : a0);
                pe[ks][4 + r] = (_Float16)(hi ? b1 : b0);
            }
        }
        #pragma unroll
        for (int mt = 0; mt < 4; mt++) {
            f32x4 t = MFMA16(wf[mt][0], pe[0], zero4());
            o[qt][mt] = MFMA16(wf[mt][1], pe[1], t);
        }
    }
    #pragma unroll
    for (int qt = 0; qt < 2; qt++) {
        const int row = rbase + qt * 16 + c;
        if (row < N_ROWS) {
            #pragma unroll
            for (int mt = 0; mt < 4; mt++) {
                const float* bp = sBv + mt * 16 + 4 * Q;
                float4 vv = make_float4(o[qt][mt][0] + bp[0], o[qt][mt][1] + bp[1],
                                        o[qt][mt][2] + bp[2], o[qt][mt][3] + bp[3]);
                *(float4*)(out + (size_t)row * 64 + mt * 16 + 4 * Q) = vv;
            }
        }
    }
}

extern "C" void kernel_launch(void* const* d_in, const int* in_sizes, int n_in,
                              void* d_out, int out_size, void* d_ws, size_t ws_size,
                              hipStream_t stream)
{
    const float* x  = (const float*)d_in[0];
    const float* nb = (const float*)d_in[1];
    const float* Wq = (const float*)d_in[2];
    const float* bq = (const float*)d_in[3];
    const float* Wk = (const float*)d_in[4];
    // d_in[5] = bk: provably cancels in softmax -> unused
    const float* Wv = (const float*)d_in[6];
    const float* bv = (const float*)d_in[7];
    float* out = (float*)d_out;

    const int grid = (N_ROWS + 127) / 128;   // 782 blocks x 256 threads
    attn_kernel<<<grid, 256, 0, stream>>>(x, nb, Wq, bq, Wk, Wv, bv, out);
}